// Round 3
// baseline (1796.524 us; speedup 1.0000x reference)
//
#include <hip/hip_runtime.h>
#include <hip/hip_bf16.h>
#include <math.h>

#define B_ 2
#define T_ 2048
#define C_ 1024
#define H_ 16
#define D_ 64

// ---------------------------------------------------------------------------
// GEMM (NT): out[M,N] = A[M,K] @ W[N,K]^T + bias[N]
// MODE 0: plain row-major [M,N] write
// MODE 1: scatter write to [B,H,T,D] (n -> h = n>>6, d = n&63; m -> b,t)
// 64x64 tile, BK=16, 256 threads, 4x4 per-thread micro-tile.
// ---------------------------------------------------------------------------
template<int MODE>
__global__ __launch_bounds__(256)
void gemm_nt(const float* __restrict__ A, const float* __restrict__ W,
             const float* __restrict__ bias, float* __restrict__ out,
             int M, int N, int K)
{
    __shared__ float As[16][64];
    __shared__ float Bs[16][64];
    const int m0 = blockIdx.x * 64;
    const int n0 = blockIdx.y * 64;
    const int t  = threadIdx.x;
    const int lrow  = t >> 2;   // 0..63
    const int lquad = t & 3;    // k-quad
    const int tx = t & 15, ty = t >> 4;
    float c[4][4] = {};
    for (int kc = 0; kc < K; kc += 16) {
        __syncthreads();
        const float4 av = *(const float4*)&A[(size_t)(m0 + lrow) * K + kc + lquad * 4];
        const float4 wv = *(const float4*)&W[(size_t)(n0 + lrow) * K + kc + lquad * 4];
        As[lquad*4+0][lrow] = av.x; As[lquad*4+1][lrow] = av.y;
        As[lquad*4+2][lrow] = av.z; As[lquad*4+3][lrow] = av.w;
        Bs[lquad*4+0][lrow] = wv.x; Bs[lquad*4+1][lrow] = wv.y;
        Bs[lquad*4+2][lrow] = wv.z; Bs[lquad*4+3][lrow] = wv.w;
        __syncthreads();
        #pragma unroll
        for (int k = 0; k < 16; ++k) {
            const float4 a4 = *(const float4*)&As[k][ty * 4];
            const float4 b4 = *(const float4*)&Bs[k][tx * 4];
            const float a[4] = {a4.x, a4.y, a4.z, a4.w};
            const float b[4] = {b4.x, b4.y, b4.z, b4.w};
            #pragma unroll
            for (int i = 0; i < 4; ++i)
                #pragma unroll
                for (int j = 0; j < 4; ++j)
                    c[i][j] = fmaf(a[i], b[j], c[i][j]);
        }
    }
    #pragma unroll
    for (int i = 0; i < 4; ++i) {
        const int m = m0 + ty * 4 + i;
        #pragma unroll
        for (int j = 0; j < 4; ++j) {
            const int n = n0 + tx * 4 + j;
            const float v = c[i][j] + bias[n];
            if (MODE == 0) {
                out[(size_t)m * N + n] = v;
            } else {
                const int b  = m >> 11;      // m / T_ (T_=2048)
                const int tt = m & 2047;     // m % T_
                const int h  = n >> 6;
                const int d  = n & 63;
                out[((((size_t)b * H_ + h) * T_ + tt) << 6) + d] = v;
            }
        }
    }
}

// ---------------------------------------------------------------------------
// Causal flash attention, fp32. One block = one (b,h) x 64 q-rows.
// 256 threads: row = t>>2 (64 rows), slot = t&3 (16 k-cols / 16 d-dims each).
// The 4 lanes of a row are consecutive lanes of one wave -> wave-synchronous
// LDS P exchange (CDNA LDS ops are in-order per wave).
// ---------------------------------------------------------------------------
#define PADW 68   // float4-aligned row stride; spreads rows across banks

__global__ __launch_bounds__(256)
void attn_fwd(const float* __restrict__ Q, const float* __restrict__ K,
              const float* __restrict__ V, float* __restrict__ out)
{
    __shared__ float Qs[64][PADW];
    __shared__ float Ks[64][PADW];
    __shared__ float Vs[64][PADW];
    __shared__ float Ps[64][PADW];
    const int bh = blockIdx.y;            // b*H + h
    const int b = bh >> 4, h = bh & 15;
    const int qt = blockIdx.x;
    const int q0 = qt * 64;
    const float* Qp = Q + ((size_t)bh * T_ + q0) * D_;
    const float* Kp = K + (size_t)bh * T_ * D_;
    const float* Vp = V + (size_t)bh * T_ * D_;
    const int t = threadIdx.x;
    const int row = t >> 2, slot = t & 3;

    // stage Q tile (64x64): 1024 float4s / 256 threads
    #pragma unroll
    for (int i = 0; i < 4; ++i) {
        const int idx = i * 256 + t;
        const int r = idx >> 4, c4 = idx & 15;
        const float4 qv = *(const float4*)&Qp[(size_t)r * D_ + c4 * 4];
        Qs[r][c4*4+0] = qv.x; Qs[r][c4*4+1] = qv.y;
        Qs[r][c4*4+2] = qv.z; Qs[r][c4*4+3] = qv.w;
    }

    float m_i = -INFINITY, l_i = 0.f;
    float4 acc[4] = {};   // d-dims slot*16 .. slot*16+15

    for (int kt = 0; kt <= qt; ++kt) {
        const int k0 = kt * 64;
        __syncthreads();
        #pragma unroll
        for (int i = 0; i < 4; ++i) {
            const int idx = i * 256 + t;
            const int r = idx >> 4, c4 = idx & 15;
            const float4 kv = *(const float4*)&Kp[(size_t)(k0 + r) * D_ + c4 * 4];
            const float4 vv = *(const float4*)&Vp[(size_t)(k0 + r) * D_ + c4 * 4];
            Ks[r][c4*4+0] = kv.x; Ks[r][c4*4+1] = kv.y;
            Ks[r][c4*4+2] = kv.z; Ks[r][c4*4+3] = kv.w;
            Vs[r][c4*4+0] = vv.x; Vs[r][c4*4+1] = vv.y;
            Vs[r][c4*4+2] = vv.z; Vs[r][c4*4+3] = vv.w;
        }
        __syncthreads();

        // S = Q K^T for my 16 k-cols
        float s[16];
        #pragma unroll
        for (int j = 0; j < 16; ++j) s[j] = 0.f;
        #pragma unroll 4
        for (int d4 = 0; d4 < 16; ++d4) {
            const float4 q4 = *(const float4*)&Qs[row][d4 * 4];
            #pragma unroll
            for (int j = 0; j < 16; ++j) {
                const float4 k4 = *(const float4*)&Ks[slot * 16 + j][d4 * 4];
                s[j] = fmaf(q4.x, k4.x, fmaf(q4.y, k4.y,
                       fmaf(q4.z, k4.z, fmaf(q4.w, k4.w, s[j]))));
            }
        }

        // scale + causal mask (only diagonal tile partially masked)
        const bool diag = (kt == qt);
        float smax = -INFINITY;
        #pragma unroll
        for (int j = 0; j < 16; ++j) {
            const int kc = slot * 16 + j;
            s[j] *= 0.125f;                       // 1/sqrt(64)
            if (diag && kc > row) s[j] = -INFINITY;
            smax = fmaxf(smax, s[j]);
        }
        smax = fmaxf(smax, __shfl_xor(smax, 1));
        smax = fmaxf(smax, __shfl_xor(smax, 2));
        const float m_new = fmaxf(m_i, smax);
        const float alpha = __expf(m_i - m_new);  // first tile: exp(-inf)=0
        float psum = 0.f;
        #pragma unroll
        for (int j = 0; j < 16; ++j) {
            const float p = __expf(s[j] - m_new); // masked -> exp(-inf)=0
            Ps[row][slot * 16 + j] = p;
            psum += p;
        }
        psum += __shfl_xor(psum, 1);
        psum += __shfl_xor(psum, 2);
        l_i = l_i * alpha + psum;
        m_i = m_new;
        #pragma unroll
        for (int q4 = 0; q4 < 4; ++q4) {
            acc[q4].x *= alpha; acc[q4].y *= alpha;
            acc[q4].z *= alpha; acc[q4].w *= alpha;
        }

        // O += P V  (P row exchanged via wave-synchronous LDS)
        #pragma unroll 8
        for (int kc = 0; kc < 64; ++kc) {
            const float p = Ps[row][kc];
            #pragma unroll
            for (int q4 = 0; q4 < 4; ++q4) {
                const float4 v4 = *(const float4*)&Vs[kc][slot * 16 + q4 * 4];
                acc[q4].x = fmaf(p, v4.x, acc[q4].x);
                acc[q4].y = fmaf(p, v4.y, acc[q4].y);
                acc[q4].z = fmaf(p, v4.z, acc[q4].z);
                acc[q4].w = fmaf(p, v4.w, acc[q4].w);
            }
        }
    }

    const float inv = 1.f / l_i;
    float* op = out + ((size_t)(b * T_ + q0 + row)) * C_ + h * D_ + slot * 16;
    #pragma unroll
    for (int q4 = 0; q4 < 4; ++q4) {
        float4 o = acc[q4];
        o.x *= inv; o.y *= inv; o.z *= inv; o.w *= inv;
        *(float4*)&op[q4 * 4] = o;
    }
}

// ---------------------------------------------------------------------------
extern "C" void kernel_launch(void* const* d_in, const int* in_sizes, int n_in,
                              void* d_out, int out_size, void* d_ws, size_t ws_size,
                              hipStream_t stream) {
    const float* x  = (const float*)d_in[0];
    const float* Wq = (const float*)d_in[1];
    const float* bq = (const float*)d_in[2];
    const float* Wk = (const float*)d_in[3];
    const float* bk = (const float*)d_in[4];
    const float* Wv = (const float*)d_in[5];
    const float* bv = (const float*)d_in[6];
    const float* Wo = (const float*)d_in[7];
    const float* bo = (const float*)d_in[8];
    float* out = (float*)d_out;

    const size_t qkv_elems = (size_t)B_ * H_ * T_ * D_;  // 4M floats
    float* qb = (float*)d_ws;
    float* kb = qb + qkv_elems;
    float* vb = kb + qkv_elems;
    float* ya = vb + qkv_elems;        // [B,T,C] attention output

    const int M = B_ * T_;             // 4096
    dim3 blk(256);
    dim3 g1(M / 64, C_ / 64);
    gemm_nt<1><<<g1, blk, 0, stream>>>(x, Wq, bq, qb, M, C_, C_);
    gemm_nt<1><<<g1, blk, 0, stream>>>(x, Wk, bk, kb, M, C_, C_);
    gemm_nt<1><<<g1, blk, 0, stream>>>(x, Wv, bv, vb, M, C_, C_);
    attn_fwd<<<dim3(T_ / 64, B_ * H_), blk, 0, stream>>>(qb, kb, vb, ya);
    gemm_nt<0><<<g1, blk, 0, stream>>>(ya, Wo, bo, out, M, C_, C_);
}

// Round 7
// 203.838 us; speedup vs baseline: 8.8135x; 8.8135x over previous
//
#include <hip/hip_runtime.h>
#include <hip/hip_bf16.h>
#include <math.h>

#define B_ 2
#define T_ 2048
#define C_ 1024
#define H_ 16
#define D_ 64

typedef __attribute__((ext_vector_type(8))) short short8;
typedef __attribute__((ext_vector_type(4))) short short4v;
typedef __attribute__((ext_vector_type(4))) float f32x4;

static __device__ __forceinline__ short f2bf(float f) {
    return (short)__builtin_bit_cast(unsigned short, __float2bfloat16(f));
}

// v_mfma_f32_16x16x32_bf16 (A,B: bf16x8 in 4 VGPRs; C/D: f32x4).
// s_nop 1 guards VALU-write -> MFMA-read operand hazard.
static __device__ __forceinline__ f32x4 mfma16(short8 a, short8 b, f32x4 c) {
    asm volatile("s_nop 1\n\tv_mfma_f32_16x16x32_bf16 %0, %1, %2, %0"
                 : "+v"(c) : "v"(a), "v"(b));
    return c;
}

// MFMA-cluster -> VALU-read-of-acc hazard guard. sched_barrier(0) fences stop
// the compiler hoisting acc-consuming VALU above the wait states (rule #18).
static __device__ __forceinline__ void mfma_drain() {
    __builtin_amdgcn_sched_barrier(0);
    asm volatile("s_nop 7\n\ts_nop 7");
    __builtin_amdgcn_sched_barrier(0);
}

// async global->LDS, 16B/lane; LDS dest is wave-uniform base (+lane*16 implicit)
static __device__ __forceinline__ void gload16(const void* g, void* l) {
    __builtin_amdgcn_global_load_lds((const __attribute__((address_space(1))) void*)g,
                                     (__attribute__((address_space(3))) void*)l, 16, 0, 0);
}

// ---------------------------------------------------------------------------
// fp32 -> bf16 pre-convert: x (4M els) + Wq/Wk/Wv/Wo (1M each), vec8 grid-stride
// ---------------------------------------------------------------------------
__global__ __launch_bounds__(256)
void cvt_all(const float* __restrict__ x,  const float* __restrict__ wq,
             const float* __restrict__ wk, const float* __restrict__ wv,
             const float* __restrict__ wo,
             short* __restrict__ xb,  short* __restrict__ wqb,
             short* __restrict__ wkb, short* __restrict__ wvb,
             short* __restrict__ wob)
{
    const int XV = 524288, WV = 131072, TOT = 1048576;   // vec8 counts
    for (int i = blockIdx.x * blockDim.x + threadIdx.x; i < TOT;
         i += gridDim.x * blockDim.x) {
        const float* s; short* d; int off;
        if (i < XV) { s = x; d = xb; off = i; }
        else {
            const int j = i - XV, r = j >> 17;
            off = j & (WV - 1);
            s = (r == 0) ? wq  : (r == 1) ? wk  : (r == 2) ? wv  : wo;
            d = (r == 0) ? wqb : (r == 1) ? wkb : (r == 2) ? wvb : wob;
        }
        const float4 f0 = *(const float4*)(s + (size_t)off * 8);
        const float4 f1 = *(const float4*)(s + (size_t)off * 8 + 4);
        short8 o;
        o[0]=f2bf(f0.x); o[1]=f2bf(f0.y); o[2]=f2bf(f0.z); o[3]=f2bf(f0.w);
        o[4]=f2bf(f1.x); o[5]=f2bf(f1.y); o[6]=f2bf(f1.z); o[7]=f2bf(f1.w);
        *(short8*)(d + (size_t)off * 8) = o;
    }
}

// ---------------------------------------------------------------------------
// bf16 NT GEMM core (m97 structure): MT*16-row x 128-col tile, BK=32,
// 4 waves (2x2 quadrants), global_load_lds(16B) linear-LDS staging,
// 2 barriers per K-step, MT*4 MFMA per wave per K-step. K fixed = 1024.
// LDS layout: row-major [rows][32] bf16 (64B rows, all b128 accesses aligned).
// ---------------------------------------------------------------------------
template<int MT>
static __device__ __forceinline__ void gemm_core_bf16(
    const short* __restrict__ A, const short* __restrict__ W,
    short* Asl, short* Bsl, int m0, int n0, f32x4 (&acc)[MT][4])
{
    const int tid = threadIdx.x;
    const int wid = tid >> 6, l = tid & 63;
    const int lr  = l & 15,  lg = l >> 4;
    const int wr  = wid >> 1, wc = wid & 1;
    const int srA = MT*8*wid + (l >> 2);   // A stage row (+16*i)
    const int srB = 32*wid  + (l >> 2);    // B stage row (+16*i)
    const int ske = (l & 3) * 8;           // k-el offset within 32
    short* lA = Asl + MT*256*wid;          // wave-uniform LDS bases
    short* lB = Bsl + 1024*wid;
    for (int kc = 0; kc < 1024; kc += 32) {
        #pragma unroll
        for (int i = 0; i < MT/2; ++i)
            gload16(&A[(size_t)(m0 + srA + 16*i) * 1024 + kc + ske], lA + 512*i);
        #pragma unroll
        for (int i = 0; i < 2; ++i)
            gload16(&W[(size_t)(n0 + srB + 16*i) * 1024 + kc + ske], lB + 512*i);
        __syncthreads();                    // drains vmcnt -> staged data visible
        short8 af[MT], bfr[4];
        #pragma unroll
        for (int mi = 0; mi < MT; ++mi)
            af[mi] = *(const short8*)&Asl[(MT*16*wr + 16*mi + lr) * 32 + lg*8];
        #pragma unroll
        for (int ni = 0; ni < 4; ++ni)
            bfr[ni] = *(const short8*)&Bsl[(64*wc + 16*ni + lr) * 32 + lg*8];
        #pragma unroll
        for (int mi = 0; mi < MT; ++mi)
            #pragma unroll
            for (int ni = 0; ni < 4; ++ni)
                acc[mi][ni] = mfma16(af[mi], bfr[ni], acc[mi][ni]);
        __syncthreads();                    // protect LDS before next stage
    }
}

// Fused QKV projection: grid (32, 24); y-block 0..7 -> Q, 8..15 -> K, 16..23 -> V.
// Q,K -> bf16 [B,H,T,D]; V -> bf16 [B,H,D,T] (transposed for attention PV).
__global__ __launch_bounds__(256)
void qkv_gemm(const short* __restrict__ xb,  const short* __restrict__ wqb,
              const short* __restrict__ wkb, const short* __restrict__ wvb,
              const float* __restrict__ bq,  const float* __restrict__ bk,
              const float* __restrict__ bv,
              short* __restrict__ q, short* __restrict__ k, short* __restrict__ v)
{
    __shared__ __attribute__((aligned(16))) short Asl[128*32];
    __shared__ __attribute__((aligned(16))) short Bsl[128*32];
    const int m0 = blockIdx.x * 128;
    const int nyg = blockIdx.y;
    const int region = nyg >> 3;           // 0:Q 1:K 2:V
    const int n0 = (nyg & 7) * 128;
    const short* W    = (region == 0) ? wqb : (region == 1) ? wkb : wvb;
    const float* bias = (region == 0) ? bq  : (region == 1) ? bk  : bv;
    f32x4 acc[4][4] = {};
    gemm_core_bf16<4>(xb, W, Asl, Bsl, m0, n0, acc);
    mfma_drain();                          // MFMA -> VALU read hazard
    const int tid = threadIdx.x;
    const int wid = tid >> 6, l = tid & 63;
    const int lr = l & 15, lg = l >> 4;
    const int wr = wid >> 1, wc = wid & 1;
    if (region < 2) {
        short* outp = (region == 0) ? q : k;
        #pragma unroll
        for (int mi = 0; mi < 4; ++mi) {
            #pragma unroll
            for (int ni = 0; ni < 4; ++ni) {
                const int n = n0 + 64*wc + 16*ni + lr;
                const float bn = bias[n];
                const int h = n >> 6, d = n & 63;
                #pragma unroll
                for (int r = 0; r < 4; ++r) {
                    const int m = m0 + 64*wr + 16*mi + 4*lg + r;
                    const int bb = m >> 11, tt = m & 2047;
                    outp[((((size_t)bb*H_ + h)*T_ + tt) << 6) + d] =
                        f2bf(acc[mi][ni][r] + bn);
                }
            }
        }
    } else {
        #pragma unroll
        for (int mi = 0; mi < 4; ++mi) {
            const int m = m0 + 64*wr + 16*mi + 4*lg;   // 4 consecutive tt
            const int bb = m >> 11, tt = m & 2047;
            #pragma unroll
            for (int ni = 0; ni < 4; ++ni) {
                const int n = n0 + 64*wc + 16*ni + lr;
                const float bn = bias[n];
                const int h = n >> 6, d = n & 63;
                short4v ov;
                #pragma unroll
                for (int r = 0; r < 4; ++r) ov[r] = f2bf(acc[mi][ni][r] + bn);
                *(short4v*)&v[((((size_t)bb*H_ + h)*D_ + d) << 11) + tt] = ov;
            }
        }
    }
}

// Output projection: ya[4096][1024] bf16 x Wo[1024][1024] bf16 -> fp32 out.
// 64x128 tile (grid 64x8 = 512 blocks) for 2 blocks/CU.
__global__ __launch_bounds__(256)
void out_gemm(const short* __restrict__ ya, const short* __restrict__ wo,
              const float* __restrict__ bo, float* __restrict__ out)
{
    __shared__ __attribute__((aligned(16))) short Asl[64*32];
    __shared__ __attribute__((aligned(16))) short Bsl[128*32];
    const int m0 = blockIdx.x * 64;
    const int n0 = blockIdx.y * 128;
    f32x4 acc[2][4] = {};
    gemm_core_bf16<2>(ya, wo, Asl, Bsl, m0, n0, acc);
    mfma_drain();
    const int tid = threadIdx.x;
    const int wid = tid >> 6, l = tid & 63;
    const int lr = l & 15, lg = l >> 4;
    const int wr = wid >> 1, wc = wid & 1;
    #pragma unroll
    for (int mi = 0; mi < 2; ++mi) {
        #pragma unroll
        for (int ni = 0; ni < 4; ++ni) {
            const int n = n0 + 64*wc + 16*ni + lr;
            const float bn = bo[n];
            #pragma unroll
            for (int r = 0; r < 4; ++r) {
                const int m = m0 + 32*wr + 16*mi + 4*lg + r;
                out[(size_t)m * C_ + n] = acc[mi][ni][r] + bn;
            }
        }
    }
}

// ---------------------------------------------------------------------------
// Causal flash attention, bf16 MFMA. Block = 4 waves; 64 q-rows; KVBLK=64.
// Swapped operands: S^T = mfma(K,Q), O^T = mfma(V^T,P) -> softmax state lane-local.
// LDS row stride 88 shorts = 176B = 11*16B: every ds b128 access 16B-aligned
// (round-5's stride 72 = 144B broke alignment on odd rows -> corrupt fragments).
// Bank offset per row = 44 dwords ≡ 12 mod 32 -> 2-way conflicts only (free).
// ---------------------------------------------------------------------------
#define PAD 88

__global__ __launch_bounds__(256)
void attn_mfma(const short* __restrict__ Q, const short* __restrict__ K,
               const short* __restrict__ Vt, short* __restrict__ out)
{
    __shared__ __attribute__((aligned(16))) short Ks[64][PAD];    // [k][d]
    __shared__ __attribute__((aligned(16))) short Vs[64][PAD];    // [d][k]
    __shared__ __attribute__((aligned(16))) short Ps[4][16][PAD]; // per-wave [q][k]

    const int id = blockIdx.x;
    const int bh = id >> 5;
    const int qt = ((id & 31) + bh) & 31;        // balance work across CUs
    const int b = bh >> 4, h = bh & 15;
    const int q0 = qt * 64;
    const int tid = threadIdx.x;
    const int w = tid >> 6, l = tid & 63;
    const int lr = l & 15, lg = l >> 4;

    const short* Qp = Q  + (size_t)bh * T_ * D_;
    const short* Kp = K  + (size_t)bh * T_ * D_;
    const short* Vp = Vt + (size_t)bh * D_ * T_;

    short8 qfrag[2];
    {
        const int qrow = q0 + 16*w + lr;
        const short* qp = Qp + (size_t)qrow * D_ + lg * 8;
        qfrag[0] = *(const short8*)(qp);
        qfrag[1] = *(const short8*)(qp + 32);
    }

    float m_i = -INFINITY, l_i = 0.f;
    f32x4 oacc[4] = {};                       // O^T[d=16mt+4lg+r][q=lr]
    const float SCL = 0.125f * 1.44269504f;   // 1/sqrt(64) * log2(e)
    const int qg = q0 + 16*w + lr;

    for (int kt = 0; kt <= qt; ++kt) {
        const int k0 = kt * 64;
        __syncthreads();
        #pragma unroll
        for (int it = 0; it < 2; ++it) {
            const int idx = it * 256 + tid;
            const int r = idx >> 3, c8 = (idx & 7) * 8;
            *(short8*)&Ks[r][c8] = *(const short8*)(Kp + (size_t)(k0 + r) * D_ + c8);
            *(short8*)&Vs[r][c8] = *(const short8*)(Vp + (size_t)r * T_ + k0 + c8);
        }
        __syncthreads();

        // QK^T (swapped): sacc[mt][r] = S^T[k=k0+16mt+4lg+r][q=lr]
        f32x4 sacc[4] = {};
        #pragma unroll
        for (int mt = 0; mt < 4; ++mt) {
            #pragma unroll
            for (int kc = 0; kc < 2; ++kc) {
                const short8 kf = *(const short8*)&Ks[16*mt + lr][32*kc + 8*lg];
                sacc[mt] = mfma16(kf, qfrag[kc], sacc[mt]);
            }
        }
        mfma_drain();                         // MFMA -> VALU read hazard

        const bool diag = (kt == qt);
        float mloc = m_i;
        float sv[16];
        #pragma unroll
        for (int mt = 0; mt < 4; ++mt)
            #pragma unroll
            for (int r = 0; r < 4; ++r) {
                float s = sacc[mt][r] * SCL;
                if (diag && (k0 + 16*mt + 4*lg + r) > qg) s = -INFINITY;
                sv[mt*4+r] = s;
                mloc = fmaxf(mloc, s);
            }
        mloc = fmaxf(mloc, __shfl_xor(mloc, 16));
        mloc = fmaxf(mloc, __shfl_xor(mloc, 32));
        const float alpha = exp2f(m_i - mloc);
        float lsum = 0.f;
        #pragma unroll
        for (int mt = 0; mt < 4; ++mt) {
            short4v pk;
            #pragma unroll
            for (int r = 0; r < 4; ++r) {
                const float p = exp2f(sv[mt*4+r] - mloc);
                lsum += p;
                pk[r] = f2bf(p);
            }
            *(short4v*)&Ps[w][lr][16*mt + 4*lg] = pk;  // P[q=lr][k]
        }
        lsum += __shfl_xor(lsum, 16);
        lsum += __shfl_xor(lsum, 32);
        l_i = l_i * alpha + lsum;
        m_i = mloc;
        #pragma unroll
        for (int mt = 0; mt < 4; ++mt) {
            oacc[mt][0] *= alpha; oacc[mt][1] *= alpha;
            oacc[mt][2] *= alpha; oacc[mt][3] *= alpha;
        }

        // PV (swapped): oacc[mt] += mfma(V^T strip, P)
        #pragma unroll
        for (int kc = 0; kc < 2; ++kc) {
            const short8 pf = *(const short8*)&Ps[w][lr][32*kc + 8*lg];
            #pragma unroll
            for (int mt = 0; mt < 4; ++mt) {
                const short8 vf = *(const short8*)&Vs[16*mt + lr][32*kc + 8*lg];
                oacc[mt] = mfma16(vf, pf, oacc[mt]);
            }
        }
    }
    mfma_drain();

    const float inv = 1.f / l_i;
    const int trow = q0 + 16*w + lr;
    short* op = out + ((size_t)(b * T_ + trow)) * C_ + h * D_;
    #pragma unroll
    for (int mt = 0; mt < 4; ++mt) {
        short4v ov;
        ov[0] = f2bf(oacc[mt][0] * inv); ov[1] = f2bf(oacc[mt][1] * inv);
        ov[2] = f2bf(oacc[mt][2] * inv); ov[3] = f2bf(oacc[mt][3] * inv);
        *(short4v*)&op[16*mt + 4*lg] = ov;
    }
}

// ---------------------------------------------------------------------------
extern "C" void kernel_launch(void* const* d_in, const int* in_sizes, int n_in,
                              void* d_out, int out_size, void* d_ws, size_t ws_size,
                              hipStream_t stream) {
    const float* x  = (const float*)d_in[0];
    const float* Wq = (const float*)d_in[1];
    const float* bq = (const float*)d_in[2];
    const float* Wk = (const float*)d_in[3];
    const float* bk = (const float*)d_in[4];
    const float* Wv = (const float*)d_in[5];
    const float* bv = (const float*)d_in[6];
    const float* Wo = (const float*)d_in[7];
    const float* bo = (const float*)d_in[8];
    float* out = (float*)d_out;

    // bf16 workspace (els): x 4M | Wq..Wo 1M each | Q,K,V^T 4M each | ya 4M = 48MB
    short* xb  = (short*)d_ws;
    short* wqb = xb  + 4194304;
    short* wkb = wqb + 1048576;
    short* wvb = wkb + 1048576;
    short* wob = wvb + 1048576;
    short* qb  = wob + 1048576;
    short* kb  = qb  + 4194304;
    short* vb  = kb  + 4194304;   // V^T [B,H,D,T]
    short* yab = vb  + 4194304;   // [B,T,C]

    cvt_all<<<1024, 256, 0, stream>>>(x, Wq, Wk, Wv, Wo, xb, wqb, wkb, wvb, wob);
    qkv_gemm<<<dim3(32, 24), 256, 0, stream>>>(xb, wqb, wkb, wvb, bq, bk, bv,
                                               qb, kb, vb);
    attn_mfma<<<dim3(1024), 256, 0, stream>>>(qb, kb, vb, yab);
    out_gemm<<<dim3(64, 8), 256, 0, stream>>>(yab, wob, bo, out);
}

// Round 8
// 199.982 us; speedup vs baseline: 8.9834x; 1.0193x over previous
//
#include <hip/hip_runtime.h>
#include <hip/hip_bf16.h>
#include <math.h>

#define B_ 2
#define T_ 2048
#define C_ 1024
#define H_ 16
#define D_ 64

typedef __attribute__((ext_vector_type(8))) short short8;
typedef __attribute__((ext_vector_type(4))) short short4v;
typedef __attribute__((ext_vector_type(4))) float f32x4;

static __device__ __forceinline__ short f2bf(float f) {
    return (short)__builtin_bit_cast(unsigned short, __float2bfloat16(f));
}

// v_mfma_f32_16x16x32_bf16 (A,B: bf16x8 in 4 VGPRs; C/D: f32x4).
// s_nop 1 guards VALU-write -> MFMA-read operand hazard.
static __device__ __forceinline__ f32x4 mfma16(short8 a, short8 b, f32x4 c) {
    asm volatile("s_nop 1\n\tv_mfma_f32_16x16x32_bf16 %0, %1, %2, %0"
                 : "+v"(c) : "v"(a), "v"(b));
    return c;
}

// MFMA-cluster -> VALU-read-of-acc hazard guard. sched_barrier(0) fences stop
// the compiler hoisting acc-consuming VALU above the wait states (rule #18).
static __device__ __forceinline__ void mfma_drain() {
    __builtin_amdgcn_sched_barrier(0);
    asm volatile("s_nop 7\n\ts_nop 7");
    __builtin_amdgcn_sched_barrier(0);
}

// async global->LDS, 16B/lane; LDS dest is wave-uniform base (+lane*16 implicit)
static __device__ __forceinline__ void gload16(const void* g, void* l) {
    __builtin_amdgcn_global_load_lds((const __attribute__((address_space(1))) void*)g,
                                     (__attribute__((address_space(3))) void*)l, 16, 0, 0);
}

// ---------------------------------------------------------------------------
// fp32 -> bf16 pre-convert: x (4M els) + Wq/Wk/Wv/Wo (1M each), vec8 grid-stride
// ---------------------------------------------------------------------------
__global__ __launch_bounds__(256)
void cvt_all(const float* __restrict__ x,  const float* __restrict__ wq,
             const float* __restrict__ wk, const float* __restrict__ wv,
             const float* __restrict__ wo,
             short* __restrict__ xb,  short* __restrict__ wqb,
             short* __restrict__ wkb, short* __restrict__ wvb,
             short* __restrict__ wob)
{
    const int XV = 524288, WV = 131072, TOT = 1048576;   // vec8 counts
    for (int i = blockIdx.x * blockDim.x + threadIdx.x; i < TOT;
         i += gridDim.x * blockDim.x) {
        const float* s; short* d; int off;
        if (i < XV) { s = x; d = xb; off = i; }
        else {
            const int j = i - XV, r = j >> 17;
            off = j & (WV - 1);
            s = (r == 0) ? wq  : (r == 1) ? wk  : (r == 2) ? wv  : wo;
            d = (r == 0) ? wqb : (r == 1) ? wkb : (r == 2) ? wvb : wob;
        }
        const float4 f0 = *(const float4*)(s + (size_t)off * 8);
        const float4 f1 = *(const float4*)(s + (size_t)off * 8 + 4);
        short8 o;
        o[0]=f2bf(f0.x); o[1]=f2bf(f0.y); o[2]=f2bf(f0.z); o[3]=f2bf(f0.w);
        o[4]=f2bf(f1.x); o[5]=f2bf(f1.y); o[6]=f2bf(f1.z); o[7]=f2bf(f1.w);
        *(short8*)(d + (size_t)off * 8) = o;
    }
}

// ---------------------------------------------------------------------------
// bf16 NT GEMM core (m97 structure): MT*16-row x 128-col tile, BK=32,
// 4 waves (2x2 quadrants), global_load_lds(16B) linear-LDS staging,
// 2 barriers per K-step, MT*4 MFMA per wave per K-step. K fixed = 1024.
// LDS layout: row-major [rows][32] bf16 (64B rows, all b128 accesses aligned).
// ---------------------------------------------------------------------------
template<int MT>
static __device__ __forceinline__ void gemm_core_bf16(
    const short* __restrict__ A, const short* __restrict__ W,
    short* Asl, short* Bsl, int m0, int n0, f32x4 (&acc)[MT][4])
{
    const int tid = threadIdx.x;
    const int wid = tid >> 6, l = tid & 63;
    const int lr  = l & 15,  lg = l >> 4;
    const int wr  = wid >> 1, wc = wid & 1;
    const int srA = MT*8*wid + (l >> 2);   // A stage row (+16*i)
    const int srB = 32*wid  + (l >> 2);    // B stage row (+16*i)
    const int ske = (l & 3) * 8;           // k-el offset within 32
    short* lA = Asl + MT*256*wid;          // wave-uniform LDS bases
    short* lB = Bsl + 1024*wid;
    for (int kc = 0; kc < 1024; kc += 32) {
        #pragma unroll
        for (int i = 0; i < MT/2; ++i)
            gload16(&A[(size_t)(m0 + srA + 16*i) * 1024 + kc + ske], lA + 512*i);
        #pragma unroll
        for (int i = 0; i < 2; ++i)
            gload16(&W[(size_t)(n0 + srB + 16*i) * 1024 + kc + ske], lB + 512*i);
        __syncthreads();                    // drains vmcnt -> staged data visible
        short8 af[MT], bfr[4];
        #pragma unroll
        for (int mi = 0; mi < MT; ++mi)
            af[mi] = *(const short8*)&Asl[(MT*16*wr + 16*mi + lr) * 32 + lg*8];
        #pragma unroll
        for (int ni = 0; ni < 4; ++ni)
            bfr[ni] = *(const short8*)&Bsl[(64*wc + 16*ni + lr) * 32 + lg*8];
        #pragma unroll
        for (int mi = 0; mi < MT; ++mi)
            #pragma unroll
            for (int ni = 0; ni < 4; ++ni)
                acc[mi][ni] = mfma16(af[mi], bfr[ni], acc[mi][ni]);
        __syncthreads();                    // protect LDS before next stage
    }
}

// Fused QKV projection: grid (32, 24); y-block 0..7 -> Q, 8..15 -> K, 16..23 -> V.
// Q,K -> bf16 [B,H,T,D]; V -> bf16 [B,H,D,T] (transposed for attention PV).
__global__ __launch_bounds__(256)
void qkv_gemm(const short* __restrict__ xb,  const short* __restrict__ wqb,
              const short* __restrict__ wkb, const short* __restrict__ wvb,
              const float* __restrict__ bq,  const float* __restrict__ bk,
              const float* __restrict__ bv,
              short* __restrict__ q, short* __restrict__ k, short* __restrict__ v)
{
    __shared__ __attribute__((aligned(16))) short Asl[128*32];
    __shared__ __attribute__((aligned(16))) short Bsl[128*32];
    const int m0 = blockIdx.x * 128;
    const int nyg = blockIdx.y;
    const int region = nyg >> 3;           // 0:Q 1:K 2:V
    const int n0 = (nyg & 7) * 128;
    const short* W    = (region == 0) ? wqb : (region == 1) ? wkb : wvb;
    const float* bias = (region == 0) ? bq  : (region == 1) ? bk  : bv;
    f32x4 acc[4][4] = {};
    gemm_core_bf16<4>(xb, W, Asl, Bsl, m0, n0, acc);
    mfma_drain();                          // MFMA -> VALU read hazard
    const int tid = threadIdx.x;
    const int wid = tid >> 6, l = tid & 63;
    const int lr = l & 15, lg = l >> 4;
    const int wr = wid >> 1, wc = wid & 1;
    if (region < 2) {
        short* outp = (region == 0) ? q : k;
        #pragma unroll
        for (int mi = 0; mi < 4; ++mi) {
            #pragma unroll
            for (int ni = 0; ni < 4; ++ni) {
                const int n = n0 + 64*wc + 16*ni + lr;
                const float bn = bias[n];
                const int h = n >> 6, d = n & 63;
                #pragma unroll
                for (int r = 0; r < 4; ++r) {
                    const int m = m0 + 64*wr + 16*mi + 4*lg + r;
                    const int bb = m >> 11, tt = m & 2047;
                    outp[((((size_t)bb*H_ + h)*T_ + tt) << 6) + d] =
                        f2bf(acc[mi][ni][r] + bn);
                }
            }
        }
    } else {
        #pragma unroll
        for (int mi = 0; mi < 4; ++mi) {
            const int m = m0 + 64*wr + 16*mi + 4*lg;   // 4 consecutive tt
            const int bb = m >> 11, tt = m & 2047;
            #pragma unroll
            for (int ni = 0; ni < 4; ++ni) {
                const int n = n0 + 64*wc + 16*ni + lr;
                const float bn = bias[n];
                const int h = n >> 6, d = n & 63;
                short4v ov;
                #pragma unroll
                for (int r = 0; r < 4; ++r) ov[r] = f2bf(acc[mi][ni][r] + bn);
                *(short4v*)&v[((((size_t)bb*H_ + h)*D_ + d) << 11) + tt] = ov;
            }
        }
    }
}

// Output projection: ya[4096][1024] bf16 x Wo[1024][1024] bf16 -> fp32 out.
// 64x128 tile (grid 64x8 = 512 blocks) for 2 blocks/CU.
__global__ __launch_bounds__(256)
void out_gemm(const short* __restrict__ ya, const short* __restrict__ wo,
              const float* __restrict__ bo, float* __restrict__ out)
{
    __shared__ __attribute__((aligned(16))) short Asl[64*32];
    __shared__ __attribute__((aligned(16))) short Bsl[128*32];
    const int m0 = blockIdx.x * 64;
    const int n0 = blockIdx.y * 128;
    f32x4 acc[2][4] = {};
    gemm_core_bf16<2>(ya, wo, Asl, Bsl, m0, n0, acc);
    mfma_drain();
    const int tid = threadIdx.x;
    const int wid = tid >> 6, l = tid & 63;
    const int lr = l & 15, lg = l >> 4;
    const int wr = wid >> 1, wc = wid & 1;
    #pragma unroll
    for (int mi = 0; mi < 2; ++mi) {
        #pragma unroll
        for (int ni = 0; ni < 4; ++ni) {
            const int n = n0 + 64*wc + 16*ni + lr;
            const float bn = bo[n];
            #pragma unroll
            for (int r = 0; r < 4; ++r) {
                const int m = m0 + 32*wr + 16*mi + 4*lg + r;
                out[(size_t)m * C_ + n] = acc[mi][ni][r] + bn;
            }
        }
    }
}

// ---------------------------------------------------------------------------
// Causal flash attention, bf16 MFMA. Block = 4 waves; 64 q-rows; KVBLK=64.
// Swapped operands: S^T = mfma(K,Q), O^T = mfma(V^T,P) -> softmax state lane-local.
// LDS row stride 88 shorts = 176B = 11*16B: b128-aligned, 2-way banks (free).
// v2 (T14 async-STAGE): per tile -> barrier; regs->LDS; barrier; ISSUE loads for
// tile kt+1 into regs; compute kt. The loads' first consumer is next iteration's
// ds_write (vmcnt drain lands there), so HBM/L2 latency hides under compute.
// Diagonal mask branch is wave-uniform: non-diag tiles skip the cmp/sel chain.
// ---------------------------------------------------------------------------
#define PAD 88

__global__ __launch_bounds__(256)
void attn_mfma(const short* __restrict__ Q, const short* __restrict__ K,
               const short* __restrict__ Vt, short* __restrict__ out)
{
    __shared__ __attribute__((aligned(16))) short Ks[64][PAD];    // [k][d]
    __shared__ __attribute__((aligned(16))) short Vs[64][PAD];    // [d][k]
    __shared__ __attribute__((aligned(16))) short Ps[4][16][PAD]; // per-wave [q][k]

    const int id = blockIdx.x;
    const int bh = id >> 5;
    const int qt = ((id & 31) + bh) & 31;        // balance work across CUs
    const int b = bh >> 4, h = bh & 15;
    const int q0 = qt * 64;
    const int tid = threadIdx.x;
    const int w = tid >> 6, l = tid & 63;
    const int lr = l & 15, lg = l >> 4;

    const short* Qp = Q  + (size_t)bh * T_ * D_;
    const short* Kp = K  + (size_t)bh * T_ * D_;
    const short* Vp = Vt + (size_t)bh * D_ * T_;

    // staging coords: thread owns rows {sr0, sr0+32}, 8-col chunk sc
    const int sr0 = tid >> 3;          // 0..31
    const int sc  = (tid & 7) * 8;     // 0..56

    // prologue: prefetch tile 0 into regs
    short8 kreg[2], vreg[2];
    kreg[0] = *(const short8*)(Kp + (size_t)sr0 * D_ + sc);
    kreg[1] = *(const short8*)(Kp + (size_t)(sr0 + 32) * D_ + sc);
    vreg[0] = *(const short8*)(Vp + (size_t)sr0 * T_ + sc);
    vreg[1] = *(const short8*)(Vp + (size_t)(sr0 + 32) * T_ + sc);

    short8 qfrag[2];
    const int qrow = q0 + 16*w + lr;
    {
        const short* qp = Qp + (size_t)qrow * D_ + lg * 8;
        qfrag[0] = *(const short8*)(qp);
        qfrag[1] = *(const short8*)(qp + 32);
    }

    float m_i = -INFINITY, l_i = 0.f;
    f32x4 oacc[4] = {};                       // O^T[d=16mt+4lg+r][q=lr]
    const float SCL = 0.125f * 1.44269504f;   // 1/sqrt(64) * log2(e)

    for (int kt = 0; kt <= qt; ++kt) {
        const int k0 = kt * 64;
        __syncthreads();                       // prev compute done reading LDS
        *(short8*)&Ks[sr0][sc]      = kreg[0]; // vmcnt drain for prefetch lands here
        *(short8*)&Ks[sr0 + 32][sc] = kreg[1];
        *(short8*)&Vs[sr0][sc]      = vreg[0];
        *(short8*)&Vs[sr0 + 32][sc] = vreg[1];
        __syncthreads();                       // LDS ready

        if (kt < qt) {                         // issue prefetch for tile kt+1
            const int k1 = k0 + 64;
            kreg[0] = *(const short8*)(Kp + (size_t)(k1 + sr0) * D_ + sc);
            kreg[1] = *(const short8*)(Kp + (size_t)(k1 + sr0 + 32) * D_ + sc);
            vreg[0] = *(const short8*)(Vp + (size_t)sr0 * T_ + k1 + sc);
            vreg[1] = *(const short8*)(Vp + (size_t)(sr0 + 32) * T_ + k1 + sc);
        }

        // QK^T (swapped): sacc[mt][r] = S^T[k=k0+16mt+4lg+r][q=lr]
        f32x4 sacc[4] = {};
        #pragma unroll
        for (int mt = 0; mt < 4; ++mt) {
            #pragma unroll
            for (int kc = 0; kc < 2; ++kc) {
                const short8 kf = *(const short8*)&Ks[16*mt + lr][32*kc + 8*lg];
                sacc[mt] = mfma16(kf, qfrag[kc], sacc[mt]);
            }
        }
        mfma_drain();                         // MFMA -> VALU read hazard

        float mloc = m_i;
        float sv[16];
        if (kt == qt) {                       // diagonal tile: apply causal mask
            #pragma unroll
            for (int mt = 0; mt < 4; ++mt)
                #pragma unroll
                for (int r = 0; r < 4; ++r) {
                    float s = sacc[mt][r] * SCL;
                    if ((k0 + 16*mt + 4*lg + r) > qrow) s = -INFINITY;
                    sv[mt*4+r] = s;
                    mloc = fmaxf(mloc, s);
                }
        } else {                              // interior tile: no mask
            #pragma unroll
            for (int mt = 0; mt < 4; ++mt)
                #pragma unroll
                for (int r = 0; r < 4; ++r) {
                    const float s = sacc[mt][r] * SCL;
                    sv[mt*4+r] = s;
                    mloc = fmaxf(mloc, s);
                }
        }
        mloc = fmaxf(mloc, __shfl_xor(mloc, 16));
        mloc = fmaxf(mloc, __shfl_xor(mloc, 32));
        const float alpha = exp2f(m_i - mloc);
        float lsum = 0.f;
        #pragma unroll
        for (int mt = 0; mt < 4; ++mt) {
            short4v pk;
            #pragma unroll
            for (int r = 0; r < 4; ++r) {
                const float p = exp2f(sv[mt*4+r] - mloc);
                lsum += p;
                pk[r] = f2bf(p);
            }
            *(short4v*)&Ps[w][lr][16*mt + 4*lg] = pk;  // P[q=lr][k]
        }
        lsum += __shfl_xor(lsum, 16);
        lsum += __shfl_xor(lsum, 32);
        l_i = l_i * alpha + lsum;
        m_i = mloc;
        #pragma unroll
        for (int mt = 0; mt < 4; ++mt) {
            oacc[mt][0] *= alpha; oacc[mt][1] *= alpha;
            oacc[mt][2] *= alpha; oacc[mt][3] *= alpha;
        }

        // PV (swapped): oacc[mt] += mfma(V^T strip, P)
        #pragma unroll
        for (int kc = 0; kc < 2; ++kc) {
            const short8 pf = *(const short8*)&Ps[w][lr][32*kc + 8*lg];
            #pragma unroll
            for (int mt = 0; mt < 4; ++mt) {
                const short8 vf = *(const short8*)&Vs[16*mt + lr][32*kc + 8*lg];
                oacc[mt] = mfma16(vf, pf, oacc[mt]);
            }
        }
    }
    mfma_drain();

    const float inv = 1.f / l_i;
    short* op = out + ((size_t)(b * T_ + qrow)) * C_ + h * D_;
    #pragma unroll
    for (int mt = 0; mt < 4; ++mt) {
        short4v ov;
        ov[0] = f2bf(oacc[mt][0] * inv); ov[1] = f2bf(oacc[mt][1] * inv);
        ov[2] = f2bf(oacc[mt][2] * inv); ov[3] = f2bf(oacc[mt][3] * inv);
        *(short4v*)&op[16*mt + 4*lg] = ov;
    }
}

// ---------------------------------------------------------------------------
extern "C" void kernel_launch(void* const* d_in, const int* in_sizes, int n_in,
                              void* d_out, int out_size, void* d_ws, size_t ws_size,
                              hipStream_t stream) {
    const float* x  = (const float*)d_in[0];
    const float* Wq = (const float*)d_in[1];
    const float* bq = (const float*)d_in[2];
    const float* Wk = (const float*)d_in[3];
    const float* bk = (const float*)d_in[4];
    const float* Wv = (const float*)d_in[5];
    const float* bv = (const float*)d_in[6];
    const float* Wo = (const float*)d_in[7];
    const float* bo = (const float*)d_in[8];
    float* out = (float*)d_out;

    // bf16 workspace (els): x 4M | Wq..Wo 1M each | Q,K,V^T 4M each | ya 4M = 48MB
    short* xb  = (short*)d_ws;
    short* wqb = xb  + 4194304;
    short* wkb = wqb + 1048576;
    short* wvb = wkb + 1048576;
    short* wob = wvb + 1048576;
    short* qb  = wob + 1048576;
    short* kb  = qb  + 4194304;
    short* vb  = kb  + 4194304;   // V^T [B,H,D,T]
    short* yab = vb  + 4194304;   // [B,T,C]

    cvt_all<<<1024, 256, 0, stream>>>(x, Wq, Wk, Wv, Wo, xb, wqb, wkb, wvb, wob);
    qkv_gemm<<<dim3(32, 24), 256, 0, stream>>>(xb, wqb, wkb, wvb, bq, bk, bv,
                                               qb, kb, vb);
    attn_mfma<<<dim3(1024), 256, 0, stream>>>(qb, kb, vb, yab);
    out_gemm<<<dim3(64, 8), 256, 0, stream>>>(yab, wob, bo, out);
}